// Round 3
// baseline (8318.724 us; speedup 1.0000x reference)
//
#include <hip/hip_runtime.h>
#include <hip/hip_fp16.h>

typedef float f32x4 __attribute__((ext_vector_type(4)));
typedef float f32x2 __attribute__((ext_vector_type(2)));

#define EMB   300
#define HID   300
#define G4    1200
#define TAGS  64
#define BB    64
#define TT    512
#define MM    (BB*TT)
#define KP    150            // k-pairs per gate stream
#define GSTRIDE (KP*HID)     // 45000 __half2 per gate

__device__ __forceinline__ float sigm(float x) {
    return 1.0f / (1.0f + __expf(-x));
}
__device__ __forceinline__ float tanh_fast(float x) {
    float e = __expf(-2.0f * fabsf(x));
    float r = (1.0f - e) / (1.0f + e);
    return copysignf(r, x);
}

// ---------------- K1: xg = emb[tokens] @ W + bias, stored fp16 --------------
// grid (512, 19, 2), block 256. Tile 64x64, K-chunk 20, 4x4 micro-tile.
__global__ __launch_bounds__(256)
void k1_xg(const int* __restrict__ tokens, const int* __restrict__ seqlen,
           const float* __restrict__ emb,
           const float* __restrict__ Wf, const float* __restrict__ bf,
           const float* __restrict__ Wb, const float* __restrict__ bb,
           __half* __restrict__ xgf, __half* __restrict__ xgb)
{
    const int z = blockIdx.z;
    const float* __restrict__ W    = z ? Wb : Wf;
    const float* __restrict__ bias = z ? bb : bf;
    __half* __restrict__ out       = z ? xgb : xgf;

    const int row0 = blockIdx.x * 64;
    const int b    = row0 >> 9;
    const int t0   = row0 & 511;
    if (t0 >= seqlen[b]) return;       // whole strip masked -> xg never used

    const int n0 = blockIdx.y * 64;

    __shared__ __align__(16) float As[20][64];
    __shared__ __align__(16) float Bs[20][64];
    __shared__ int toks[64];

    const int tid = threadIdx.x;
    if (tid < 64) toks[tid] = tokens[row0 + tid];
    __syncthreads();

    const int tx = tid & 15, ty = tid >> 4;
    const int rm = ty * 4,   cn = tx * 4;

    float acc[4][4] = {{0.f}};

    const int ar  = tid & 63;
    const int ak0 = (tid >> 6) * 5;

    for (int kc = 0; kc < EMB; kc += 20) {
        const float* arow = emb + (size_t)toks[ar] * EMB + (kc + ak0);
        #pragma unroll
        for (int u = 0; u < 5; ++u) As[ak0 + u][ar] = arow[u];
        const int colb = n0 + ar;
        #pragma unroll
        for (int u = 0; u < 5; ++u) {
            float v = 0.f;
            if (colb < G4) v = W[(size_t)(kc + ak0 + u) * G4 + colb];
            Bs[ak0 + u][ar] = v;
        }
        __syncthreads();
        #pragma unroll
        for (int k = 0; k < 20; ++k) {
            f32x4 av = *(const f32x4*)&As[k][rm];
            f32x4 bv = *(const f32x4*)&Bs[k][cn];
            #pragma unroll
            for (int i = 0; i < 4; ++i)
                #pragma unroll
                for (int j = 0; j < 4; ++j)
                    acc[i][j] = fmaf(av[i], bv[j], acc[i][j]);
        }
        __syncthreads();
    }
    #pragma unroll
    for (int i = 0; i < 4; ++i) {
        const int row = row0 + rm + i;
        #pragma unroll
        for (int j = 0; j < 4; ++j) {
            const int col = n0 + cn + j;
            if (col < G4)
                out[(size_t)row * G4 + col] = __float2half(acc[i][j] + bias[col]);
        }
    }
}

// ---------------- kU: repack U -> fp16, gate-major, k-paired ----------------
// Upk[dir][g][kp][j] = half2( U[2kp][g*300+j], U[2kp+1][g*300+j] )
__global__ __launch_bounds__(256)
void kU_pack(const float* __restrict__ Uf, const float* __restrict__ Ub,
             __half2* __restrict__ Upkf, __half2* __restrict__ Upkb)
{
    const int idx = blockIdx.x * 256 + threadIdx.x;
    if (idx >= 2 * 4 * GSTRIDE) return;
    const int dir = idx / (4 * GSTRIDE);
    const int r   = idx % (4 * GSTRIDE);
    const int g   = r / GSTRIDE;
    const int r2  = r % GSTRIDE;
    const int kp  = r2 / HID;
    const int j   = r2 % HID;
    const float* __restrict__ U = dir ? Ub : Uf;
    const int col = g * HID + j;
    const float lo = U[(size_t)(2 * kp)     * G4 + col];
    const float hi = U[(size_t)(2 * kp + 1) * G4 + col];
    __half2* __restrict__ dst = dir ? Upkb : Upkf;
    dst[r] = __halves2half2(__float2half(lo), __float2half(hi));
}

// ---------------- kInit: out[r][c] = bfc[c] ---------------------------------
__global__ __launch_bounds__(256)
void k_init(float* __restrict__ out, const float* __restrict__ bfc)
{
    const size_t i = (size_t)blockIdx.x * 256 + threadIdx.x;
    out[i] = bfc[i & 63];
}

// ---------------- K2: LSTM scans, single barrier/step, fused FC -------------
// 64 blocks = 32 batch-pairs x 2 dirs, 448 threads.
//   tid 0..299   : thread j computes ALL FOUR gate dots for hidden unit j
//                  (both batches), applies nonlinearity, updates h (LDS,
//                  double-buffered) and c (register). U streamed fp16
//                  gate-major from L2 (720 KB/step, the per-CU BW bound).
//   tid 320..447 : project previous step's h through Wfc half (LDS) and
//                  atomicAdd into out, overlapped with the dot phase.
// ONE __syncthreads per step.
__global__ __launch_bounds__(448)
void k2_rnn(const int* __restrict__ seqlen,
            const __half2* __restrict__ Upkf, const __half2* __restrict__ Upkb,
            const __half* __restrict__ xgf, const __half* __restrict__ xgb,
            const float* __restrict__ Wfc, float* __restrict__ out)
{
    const int w    = blockIdx.x;
    const int dir  = w & 1;
    const int pair = w >> 1;
    const int bA   = pair * 2, bBt = pair * 2 + 1;
    const int LA   = seqlen[bA], LB = seqlen[bBt];
    const int maxL = LA > LB ? LA : LB;
    const __half2* __restrict__ Up = dir ? Upkb : Upkf;
    const __half* __restrict__ xg  = dir ? xgb  : xgf;

    __shared__ __align__(16) float W2s[HID][TAGS];    // 76.8 KB
    __shared__ __align__(16) float hsh[2][2][HID];    // [buf][batch][j]

    const int tid = threadIdx.x;
    for (int i = tid; i < HID * TAGS; i += 448)
        W2s[i >> 6][i & 63] = Wfc[(size_t)dir * HID * TAGS + i];
    for (int i = tid; i < 2 * 2 * HID; i += 448)
        ((float*)hsh)[i] = 0.f;
    __syncthreads();

    float cA = 0.f, cB = 0.f;

    // projection thread identity (tid 320..447)
    const int  p    = tid - 320;
    const int  bsel = (tid >= 384) ? 1 : 0;
    const int  col  = tid & 63;
    const int  bprj = bsel ? bBt : bA;

    for (int ti = 0; ti < maxL; ++ti) {
        const int tf = dir ? (maxL - 1 - ti) : ti;
        const int rb = ti & 1;
        const float* hA  = hsh[rb][0];
        const float* hB  = hsh[rb][1];
        float*       hW0 = hsh[rb ^ 1][0];
        float*       hW1 = hsh[rb ^ 1][1];

        if (tid < 300) {
            const int j = tid;
            const __half* xA = xg + ((size_t)bA  * TT + tf) * G4 + j;
            const __half* xB = xg + ((size_t)bBt * TT + tf) * G4 + j;
            float gA0 = __half2float(xA[0]);
            float gA1 = __half2float(xA[300]);
            float gA2 = __half2float(xA[600]);
            float gA3 = __half2float(xA[900]);
            float gB0 = __half2float(xB[0]);
            float gB1 = __half2float(xB[300]);
            float gB2 = __half2float(xB[600]);
            float gB3 = __half2float(xB[900]);

            const __half2* u0 = Up + j;
            const __half2* u1 = Up + GSTRIDE + j;
            const __half2* u2 = Up + 2 * GSTRIDE + j;
            const __half2* u3 = Up + 3 * GSTRIDE + j;

            #pragma unroll 5
            for (int kp = 0; kp < KP; ++kp) {
                const int o = kp * HID;
                f32x2 ha = *(const f32x2*)&hA[2 * kp];
                f32x2 hb = *(const f32x2*)&hB[2 * kp];
                __half2 w0 = u0[o], w1 = u1[o], w2 = u2[o], w3 = u3[o];
                float w0l = __half2float(w0.x), w0h = __half2float(w0.y);
                float w1l = __half2float(w1.x), w1h = __half2float(w1.y);
                float w2l = __half2float(w2.x), w2h = __half2float(w2.y);
                float w3l = __half2float(w3.x), w3h = __half2float(w3.y);
                gA0 = fmaf(w0l, ha.x, gA0); gA0 = fmaf(w0h, ha.y, gA0);
                gA1 = fmaf(w1l, ha.x, gA1); gA1 = fmaf(w1h, ha.y, gA1);
                gA2 = fmaf(w2l, ha.x, gA2); gA2 = fmaf(w2h, ha.y, gA2);
                gA3 = fmaf(w3l, ha.x, gA3); gA3 = fmaf(w3h, ha.y, gA3);
                gB0 = fmaf(w0l, hb.x, gB0); gB0 = fmaf(w0h, hb.y, gB0);
                gB1 = fmaf(w1l, hb.x, gB1); gB1 = fmaf(w1h, hb.y, gB1);
                gB2 = fmaf(w2l, hb.x, gB2); gB2 = fmaf(w2h, hb.y, gB2);
                gB3 = fmaf(w3l, hb.x, gB3); gB3 = fmaf(w3h, hb.y, gB3);
            }
            {
                float i_ = sigm(gA0), f_ = sigm(gA1);
                float z_ = tanh_fast(gA2), o_ = sigm(gA3);
                float cn = f_ * cA + i_ * z_;
                float hn = o_ * tanh_fast(cn);
                if (tf < LA) cA = cn; else hn = hA[j];
                hW0[j] = hn;
            }
            {
                float i_ = sigm(gB0), f_ = sigm(gB1);
                float z_ = tanh_fast(gB2), o_ = sigm(gB3);
                float cn = f_ * cB + i_ * z_;
                float hn = o_ * tanh_fast(cn);
                if (tf < LB) cB = cn; else hn = hB[j];
                hW1[j] = hn;
            }
        } else if (p >= 0 && ti > 0) {
            // project h of previous step (read buffer rb, no race with hW)
            const float* hs = hsh[rb][bsel];
            float acc = 0.f;
            for (int j2 = 0; j2 < HID; j2 += 4) {
                f32x4 h4 = *(const f32x4*)&hs[j2];
                acc = fmaf(h4.x, W2s[j2 + 0][col], acc);
                acc = fmaf(h4.y, W2s[j2 + 1][col], acc);
                acc = fmaf(h4.z, W2s[j2 + 2][col], acc);
                acc = fmaf(h4.w, W2s[j2 + 3][col], acc);
            }
            const int rowp = dir ? (tf + 1) : (tf - 1);
            atomicAdd(out + ((size_t)bprj * TT + rowp) * TAGS + col, acc);
        }
        __syncthreads();
    }

    // final projection (h of step maxL-1 is in buffer maxL&1) + tail fill
    if (p >= 0) {
        const float* hs = hsh[maxL & 1][bsel];
        float acc = 0.f;
        for (int j2 = 0; j2 < HID; j2 += 4) {
            f32x4 h4 = *(const f32x4*)&hs[j2];
            acc = fmaf(h4.x, W2s[j2 + 0][col], acc);
            acc = fmaf(h4.y, W2s[j2 + 1][col], acc);
            acc = fmaf(h4.z, W2s[j2 + 2][col], acc);
            acc = fmaf(h4.w, W2s[j2 + 3][col], acc);
        }
        if (dir == 0) {
            // fwd: rows [maxL-1, 512) carry the final/frozen h projection
            float* o = out + (size_t)bprj * TT * TAGS + col;
            for (int t = maxL - 1; t < TT; ++t)
                atomicAdd(o + (size_t)t * TAGS, acc);
        } else {
            // bwd: final scan step is t=0; tail rows t>=maxL contribute 0
            atomicAdd(out + (size_t)bprj * TT * TAGS + col, acc);
        }
    }
}

extern "C" void kernel_launch(void* const* d_in, const int* in_sizes, int n_in,
                              void* d_out, int out_size, void* d_ws, size_t ws_size,
                              hipStream_t stream)
{
    const int*   tokens = (const int*)d_in[0];
    const int*   seqlen = (const int*)d_in[1];
    const float* emb    = (const float*)d_in[2];
    const float* Wf     = (const float*)d_in[3];
    const float* Uf     = (const float*)d_in[4];
    const float* bf     = (const float*)d_in[5];
    const float* Wb     = (const float*)d_in[6];
    const float* Ub     = (const float*)d_in[7];
    const float* bb     = (const float*)d_in[8];
    const float* Wfc    = (const float*)d_in[9];
    const float* bfc    = (const float*)d_in[10];
    float* out = (float*)d_out;

    // ws layout: xgf fp16 [M*G4] | xgb fp16 [M*G4] | Upkf | Upkb (720 KB each)
    const size_t xg_elems = (size_t)MM * G4;
    const size_t need = xg_elems * 2 * sizeof(__half)
                      + (size_t)2 * 4 * GSTRIDE * sizeof(__half2);
    if (ws_size < need) {
        hipMemsetAsync(d_out, 0, (size_t)out_size * sizeof(float), stream);
        return;
    }
    __half*  xgf  = (__half*)d_ws;
    __half*  xgb  = xgf + xg_elems;
    __half2* Upkf = (__half2*)(xgb + xg_elems);
    __half2* Upkb = Upkf + 4 * GSTRIDE;

    hipLaunchKernelGGL(kU_pack, dim3((2 * 4 * GSTRIDE + 255) / 256), dim3(256),
                       0, stream, Uf, Ub, Upkf, Upkb);
    hipLaunchKernelGGL(k_init, dim3(MM * TAGS / 256), dim3(256), 0, stream,
                       out, bfc);
    dim3 g1(MM / 64, (G4 + 63) / 64, 2);
    hipLaunchKernelGGL(k1_xg, g1, dim3(256), 0, stream,
                       tokens, seqlen, emb, Wf, bf, Wb, bb, xgf, xgb);
    hipLaunchKernelGGL(k2_rnn, dim3(64), dim3(448), 0, stream,
                       seqlen, Upkf, Upkb, xgf, xgb, Wfc, out);
}

// Round 4
// 6758.514 us; speedup vs baseline: 1.2309x; 1.2309x over previous
//
#include <hip/hip_runtime.h>
#include <hip/hip_fp16.h>

typedef float f32x4 __attribute__((ext_vector_type(4)));

#define EMB   300
#define HID   300
#define G4    1200
#define TAGS  64
#define BB    64
#define TT    512
#define MM    (BB*TT)
#define KC    75             // k-chunks of 4 (300 = 75*4)

__device__ __forceinline__ float sigm(float x) {
    return 1.0f / (1.0f + __expf(-x));
}
__device__ __forceinline__ float tanh_fast(float x) {
    float e = __expf(-2.0f * fabsf(x));
    float r = (1.0f - e) / (1.0f + e);
    return copysignf(r, x);
}

// ---------------- K1: xg = emb[tokens] @ W + bias, stored fp16 --------------
__global__ __launch_bounds__(256)
void k1_xg(const int* __restrict__ tokens, const int* __restrict__ seqlen,
           const float* __restrict__ emb,
           const float* __restrict__ Wf, const float* __restrict__ bf,
           const float* __restrict__ Wb, const float* __restrict__ bb,
           __half* __restrict__ xgf, __half* __restrict__ xgb)
{
    const int z = blockIdx.z;
    const float* __restrict__ W    = z ? Wb : Wf;
    const float* __restrict__ bias = z ? bb : bf;
    __half* __restrict__ out       = z ? xgb : xgf;

    const int row0 = blockIdx.x * 64;
    const int b    = row0 >> 9;
    const int t0   = row0 & 511;
    if (t0 >= seqlen[b]) return;       // whole strip masked -> xg never used

    const int n0 = blockIdx.y * 64;

    __shared__ __align__(16) float As[20][64];
    __shared__ __align__(16) float Bs[20][64];
    __shared__ int toks[64];

    const int tid = threadIdx.x;
    if (tid < 64) toks[tid] = tokens[row0 + tid];
    __syncthreads();

    const int tx = tid & 15, ty = tid >> 4;
    const int rm = ty * 4,   cn = tx * 4;

    float acc[4][4] = {{0.f}};

    const int ar  = tid & 63;
    const int ak0 = (tid >> 6) * 5;

    for (int kc = 0; kc < EMB; kc += 20) {
        const float* arow = emb + (size_t)toks[ar] * EMB + (kc + ak0);
        #pragma unroll
        for (int u = 0; u < 5; ++u) As[ak0 + u][ar] = arow[u];
        const int colb = n0 + ar;
        #pragma unroll
        for (int u = 0; u < 5; ++u) {
            float v = 0.f;
            if (colb < G4) v = W[(size_t)(kc + ak0 + u) * G4 + colb];
            Bs[ak0 + u][ar] = v;
        }
        __syncthreads();
        #pragma unroll
        for (int k = 0; k < 20; ++k) {
            f32x4 av = *(const f32x4*)&As[k][rm];
            f32x4 bv = *(const f32x4*)&Bs[k][cn];
            #pragma unroll
            for (int i = 0; i < 4; ++i)
                #pragma unroll
                for (int j = 0; j < 4; ++j)
                    acc[i][j] = fmaf(av[i], bv[j], acc[i][j]);
        }
        __syncthreads();
    }
    #pragma unroll
    for (int i = 0; i < 4; ++i) {
        const int row = row0 + rm + i;
        #pragma unroll
        for (int j = 0; j < 4; ++j) {
            const int col = n0 + cn + j;
            if (col < G4)
                out[(size_t)row * G4 + col] = __float2half(acc[i][j] + bias[col]);
        }
    }
}

// ---------------- kU: repack U -> fp16, [kc][col] half4 ---------------------
// Upk[dir][kc][col] = half4( U[4kc+0][col] .. U[4kc+3][col] )  (8B per entry)
__global__ __launch_bounds__(256)
void kU_pack(const float* __restrict__ Uf, const float* __restrict__ Ub,
             uint2* __restrict__ Upkf, uint2* __restrict__ Upkb)
{
    const int idx = blockIdx.x * 256 + threadIdx.x;
    if (idx >= 2 * KC * G4) return;
    const int dir = idx / (KC * G4);
    const int r   = idx % (KC * G4);
    const int kc  = r / G4;
    const int col = r % G4;
    const float* __restrict__ U = dir ? Ub : Uf;
    __half2 lo = __floats2half2_rn(U[(size_t)(4 * kc + 0) * G4 + col],
                                   U[(size_t)(4 * kc + 1) * G4 + col]);
    __half2 hi = __floats2half2_rn(U[(size_t)(4 * kc + 2) * G4 + col],
                                   U[(size_t)(4 * kc + 3) * G4 + col]);
    uint2 v;
    v.x = *(unsigned int*)&lo;
    v.y = *(unsigned int*)&hi;
    (dir ? Upkb : Upkf)[r] = v;
}

// ---------------- kInit: out[r][c] = bfc[c] ---------------------------------
__global__ __launch_bounds__(256)
void k_init(float* __restrict__ out, const float* __restrict__ bfc)
{
    const size_t i = (size_t)blockIdx.x * 256 + threadIdx.x;
    out[i] = bfc[i & 63];
}

// ---------------- K2: LSTM scans, 1 chain/block, fused FC -------------------
// 128 blocks = 64 batches x 2 dirs, 704 threads.
//   tid 0..599   : dot threads. Thread t owns gate-cols t and t+600
//                  (t<300: i & cc of unit t; t in [300,600): f & o of unit
//                  t-300). Full 300-k dot, U streamed fp16 via 8B coalesced
//                  loads ([kc][col] half4 layout). Threads >=300 hand their
//                  (f,o) dots to partner via LDS; threads <300 do the
//                  nonlinearity, keep c in register, write h (double-buffered
//                  LDS). Loop runs exactly L steps: no masking needed.
//   tid 640..703 : project previous step's h through Wfc half (LDS) and
//                  atomicAdd into out, overlapped with the dot phase.
__global__ __launch_bounds__(704)
void k2_rnn(const int* __restrict__ seqlen,
            const uint2* __restrict__ Upkf, const uint2* __restrict__ Upkb,
            const __half* __restrict__ xgf, const __half* __restrict__ xgb,
            const float* __restrict__ Wfc, float* __restrict__ out)
{
    const int w   = blockIdx.x;
    const int dir = w & 1;
    const int b   = w >> 1;
    const int L   = seqlen[b];
    const uint2* __restrict__ Up  = dir ? Upkb : Upkf;
    const __half* __restrict__ xg = dir ? xgb  : xgf;

    __shared__ __align__(16) float  W2s[HID][TAGS];   // 76.8 KB
    __shared__ __align__(16) float  hsh[2][HID];      // double-buffered h
    __shared__ __align__(16) float2 sfo[HID];         // f,o dot handoff

    const int tid = threadIdx.x;
    for (int i = tid; i < HID * TAGS; i += 704)
        W2s[i >> 6][i & 63] = Wfc[(size_t)dir * HID * TAGS + i];
    for (int i = tid; i < 2 * HID; i += 704)
        ((float*)hsh)[i] = 0.f;
    __syncthreads();

    float c = 0.f;
    const int t    = tid;
    const int pcol = tid - 640;     // proj col if >= 0

    for (int ti = 0; ti < L; ++ti) {
        const int tf = dir ? (L - 1 - ti) : ti;
        const int rb = ti & 1;
        const float* hR = hsh[rb];
        float*       hW = hsh[rb ^ 1];

        float dA = 0.f, dC = 0.f;
        if (t < 600) {
            const __half* xr = xg + ((size_t)b * TT + tf) * G4;
            dA = __half2float(xr[t]);
            dC = __half2float(xr[t + 600]);
            #pragma unroll 5
            for (int kc = 0; kc < KC; ++kc) {
                f32x4 h4 = *(const f32x4*)&hR[kc * 4];
                uint2 ua = Up[(size_t)kc * G4 + t];
                uint2 uc = Up[(size_t)kc * G4 + t + 600];
                float2 a01 = __half22float2(*(const __half2*)&ua.x);
                float2 a23 = __half22float2(*(const __half2*)&ua.y);
                float2 c01 = __half22float2(*(const __half2*)&uc.x);
                float2 c23 = __half22float2(*(const __half2*)&uc.y);
                dA = fmaf(a01.x, h4.x, dA); dA = fmaf(a01.y, h4.y, dA);
                dA = fmaf(a23.x, h4.z, dA); dA = fmaf(a23.y, h4.w, dA);
                dC = fmaf(c01.x, h4.x, dC); dC = fmaf(c01.y, h4.y, dC);
                dC = fmaf(c23.x, h4.z, dC); dC = fmaf(c23.y, h4.w, dC);
            }
            if (t >= 300) sfo[t - 300] = make_float2(dA, dC);
        } else if (pcol >= 0 && ti > 0) {
            // project h of previous step (buffer rb)
            float acc = 0.f;
            for (int j2 = 0; j2 < HID; j2 += 4) {
                f32x4 h4 = *(const f32x4*)&hR[j2];
                acc = fmaf(h4.x, W2s[j2 + 0][pcol], acc);
                acc = fmaf(h4.y, W2s[j2 + 1][pcol], acc);
                acc = fmaf(h4.z, W2s[j2 + 2][pcol], acc);
                acc = fmaf(h4.w, W2s[j2 + 3][pcol], acc);
            }
            const int rowp = dir ? (tf + 1) : (tf - 1);
            atomicAdd(out + ((size_t)b * TT + rowp) * TAGS + pcol, acc);
        }
        __syncthreads();
        if (t < 300) {
            float2 fo = sfo[t];
            float si = sigm(dA);
            float z  = tanh_fast(dC);
            float sf = sigm(fo.x);
            float so = sigm(fo.y);
            c = fmaf(sf, c, si * z);
            hW[t] = so * tanh_fast(c);
        }
        __syncthreads();
    }

    // final projection (h of step L-1 is in buffer L&1) + tail fill
    if (pcol >= 0) {
        const float* hs = hsh[L & 1];
        float acc = 0.f;
        for (int j2 = 0; j2 < HID; j2 += 4) {
            f32x4 h4 = *(const f32x4*)&hs[j2];
            acc = fmaf(h4.x, W2s[j2 + 0][pcol], acc);
            acc = fmaf(h4.y, W2s[j2 + 1][pcol], acc);
            acc = fmaf(h4.z, W2s[j2 + 2][pcol], acc);
            acc = fmaf(h4.w, W2s[j2 + 3][pcol], acc);
        }
        if (dir == 0) {
            // fwd: rows [L-1, 512) all carry the final/frozen h projection
            float* o = out + (size_t)b * TT * TAGS + pcol;
            for (int tt = L - 1; tt < TT; ++tt)
                atomicAdd(o + (size_t)tt * TAGS, acc);
        } else {
            // bwd: final scan step is t=0; rows >= L contribute exactly 0
            atomicAdd(out + (size_t)b * TT * TAGS + pcol, acc);
        }
    }
}

extern "C" void kernel_launch(void* const* d_in, const int* in_sizes, int n_in,
                              void* d_out, int out_size, void* d_ws, size_t ws_size,
                              hipStream_t stream)
{
    const int*   tokens = (const int*)d_in[0];
    const int*   seqlen = (const int*)d_in[1];
    const float* emb    = (const float*)d_in[2];
    const float* Wf     = (const float*)d_in[3];
    const float* Uf     = (const float*)d_in[4];
    const float* bf     = (const float*)d_in[5];
    const float* Wb     = (const float*)d_in[6];
    const float* Ub     = (const float*)d_in[7];
    const float* bb     = (const float*)d_in[8];
    const float* Wfc    = (const float*)d_in[9];
    const float* bfc    = (const float*)d_in[10];
    float* out = (float*)d_out;

    // ws layout: xgf fp16 [M*G4] | xgb fp16 [M*G4] | Upkf | Upkb (720 KB each)
    const size_t xg_elems = (size_t)MM * G4;
    const size_t need = xg_elems * 2 * sizeof(__half)
                      + (size_t)2 * KC * G4 * sizeof(uint2);
    if (ws_size < need) {
        hipMemsetAsync(d_out, 0, (size_t)out_size * sizeof(float), stream);
        return;
    }
    __half* xgf  = (__half*)d_ws;
    __half* xgb  = xgf + xg_elems;
    uint2*  Upkf = (uint2*)(xgb + xg_elems);
    uint2*  Upkb = Upkf + (size_t)KC * G4;

    hipLaunchKernelGGL(kU_pack, dim3((2 * KC * G4 + 255) / 256), dim3(256),
                       0, stream, Uf, Ub, Upkf, Upkb);
    hipLaunchKernelGGL(k_init, dim3(MM * TAGS / 256), dim3(256), 0, stream,
                       out, bfc);
    dim3 g1(MM / 64, (G4 + 63) / 64, 2);
    hipLaunchKernelGGL(k1_xg, g1, dim3(256), 0, stream,
                       tokens, seqlen, emb, Wf, bf, Wb, bb, xgf, xgb);
    hipLaunchKernelGGL(k2_rnn, dim3(128), dim3(704), 0, stream,
                       seqlen, Upkf, Upkb, xgf, xgb, Wfc, out);
}